// Round 3
// baseline (350.646 us; speedup 1.0000x reference)
//
#include <hip/hip_runtime.h>

// Problem constants
#define V_CNT   10475
#define M_A     704
#define N_A     128
#define KB      10
#define D_TOT   270336       // 704*128*3
#define ROW384  384          // 128*3 floats per m-row of a pc row
#define NCHUNK  22           // 704 / MT
#define MT      32           // m-tile in k_main
#define LSTR    388          // LDS row stride: 388%32=4 breaks bank conflicts, %4==0 keeps float4 alignment

// ws layout (float offsets)
#define WS_JJ     0          // 33: Jv[3], JB[3][10]
#define WS_CMEAN  64         // 128
#define WS_MC     192        // 384
#define WS_V2C    576        // 3*128 = 384   V2c[c][p] = sum_m V2[p][m][c]
#define WS_SASUM  960        // 64*3          sum_m sa0[b][m][c]
#define WS_GWS    1152       // 64*128 = 8192 gamma partial sums (atomic)
#define WS_UT     9344       // 384*128 = 49152  Ut[nc][p] (atomic)
#define WS_X      58496      // 64*2496: [obj(384); sa0(2112)] per b
#define WS_TOTAL  218240     // floats (873 KB)
#define WS_ZEROF  58496      // zero everything before X (all atomic targets)

#define NJ_BLK 28
#define NM_BLK 88
#define NP_BLK 64

typedef float f4v __attribute__((ext_vector_type(4)));

// ---------------------------------------------------------------- K1: fused precompute
// blocks [0,28): J-reduce; [28,116): Mc-reduce; [116,180): per-b prep (obj + sa0 + saSum)
__global__ __launch_bounds__(384) void k_pre(
    const float* __restrict__ Jr, const float* __restrict__ vt,
    const float* __restrict__ sd, const float* __restrict__ mean,
    const float* __restrict__ betas, const float* __restrict__ rot,
    const float* __restrict__ trans, const float* __restrict__ org,
    const int* __restrict__ anch,
    float* __restrict__ JJ, float* __restrict__ Mc,
    float* __restrict__ X, float* __restrict__ saSum) {
  __shared__ float orgL[384];
  __shared__ float red[384];
  __shared__ float small[24];  // 0..9 betas, 10..18 rot, 19..21 trans
  const int blk = blockIdx.x, t = threadIdx.x;

  if (blk < NJ_BLK) {
    float acc[33];
#pragma unroll
    for (int i = 0; i < 33; ++i) acc[i] = 0.f;
    int v = blk * 384 + t;
    if (v < V_CNT) {
      float jr = Jr[v];
#pragma unroll
      for (int c = 0; c < 3; ++c) {
        acc[c] += jr * vt[v * 3 + c];
        const float* sp = sd + ((size_t)v * 3 + c) * KB;
#pragma unroll
        for (int k = 0; k < KB; ++k) acc[3 + c * KB + k] += jr * sp[k];
      }
    }
#pragma unroll
    for (int i = 0; i < 33; ++i) {
      float x = acc[i];
      for (int off = 32; off > 0; off >>= 1) x += __shfl_down(x, off);
      if ((t & 63) == 0) atomicAdd(&JJ[i], x);
    }
  } else if (blk < NJ_BLK + NM_BLK) {
    int j = blk - NJ_BLK;
    float a = 0.f;
#pragma unroll
    for (int mi = 0; mi < 8; ++mi)
      a += mean[(size_t)(j * 8 + mi) * ROW384 + t];
    atomicAdd(&Mc[t], a);
  } else {
    const int b = blk - (NJ_BLK + NM_BLK);
    if (t < 10) small[t] = betas[b * 10 + t];
    else if (t >= 10 && t < 19) small[t] = rot[b * 9 + (t - 10)];
    else if (t >= 19 && t < 22) small[t] = trans[b * 3 + (t - 19)];
    orgL[t] = org[(size_t)b * 384 + t];
    __syncthreads();
    {
      int n = t / 3, d = t % 3;
      X[(size_t)b * 2496 + t] =
          orgL[n * 3 + 0] * small[10 + d * 3 + 0] +
          orgL[n * 3 + 1] * small[10 + d * 3 + 1] +
          orgL[n * 3 + 2] * small[10 + d * 3 + 2] + small[19 + d];
    }
    float ps = 0.f;
    for (int e = t; e < 2112; e += 384) {
      int m = e / 3, c = e % 3;
      int a = anch[m];
      const float* sp = sd + ((size_t)a * 3 + c) * KB;
      float val = vt[a * 3 + c];
#pragma unroll
      for (int k = 0; k < KB; ++k) val += small[k] * sp[k];
      X[(size_t)b * 2496 + 384 + e] = val;
      ps += val;
    }
    red[t] = ps;
    __syncthreads();
    if (t < 3) {
      float s = 0.f;
#pragma unroll 8
      for (int j = 0; j < 128; ++j) s += red[t + 3 * j];
      saSum[b * 3 + t] = s;
    }
  }
}

// ---------------------------------------------------------------- K2: single pass over pca_components
// block = (chunk, pid). Computes, from its 32x384 tile of pc row pid:
//   Ut[nc][pid]   += sum_m tile            (atomic, also kept in LDS ycat[0:384))
//   vbn[mc]        = -sum_n tile           (LDS ycat[384:480), NOT materialized globally)
//   cmean[pid]    += tile . mean-tile      (atomic)
//   V2c[c][pid]   += sum_m V2              (atomic)
//   gWS[b][pid]   += Ublk.obj[b] - Vblk.sa0[b]   for all 64 b  (atomic)  <- replaces k_gamma
__global__ __launch_bounds__(384) void k_main(
    const float* __restrict__ pc, const float* __restrict__ mean,
    const float* __restrict__ X,
    float* __restrict__ Ut, float* __restrict__ V2c,
    float* __restrict__ cmean, float* __restrict__ gWS) {
  __shared__ float tile[MT * LSTR];  // 49,664 B
  __shared__ float ycat[480];        // [0,384)=Ublk, [384,480)=-Vblk
  __shared__ float red[384];
  __shared__ float cred[6];
  const int t = threadIdx.x;
  const int pid = blockIdx.x & 127;
  const int chunk = blockIdx.x >> 7;  // 0..21
  const int m0 = chunk * MT;
  const float* row = pc + (size_t)pid * D_TOT + (size_t)m0 * ROW384;
  const float* mrow = mean + (size_t)m0 * ROW384;

  float cm = 0.f;
#pragma unroll
  for (int i = 0; i < 8; ++i) {
    int f = 1536 * i + 4 * t;
    f4v pv = __builtin_nontemporal_load((const f4v*)(row + f));  // pc is read exactly once: keep L2 for mean/X/Ut
    float4 mv = *(const float4*)(mrow + f);
    cm += pv[0] * mv.x + pv[1] * mv.y + pv[2] * mv.z + pv[3] * mv.w;
    int m_l = 4 * i + t / 96;
    int col = (t % 96) * 4;
    *(f4v*)(&tile[m_l * LSTR + col]) = pv;
  }
  __syncthreads();  // S1

  // U partial: fixed (n,c)=t, sum over 32 m
  {
    float u = 0.f;
#pragma unroll
    for (int m = 0; m < MT; ++m) u += tile[m * LSTR + t];
    ycat[t] = u;
    atomicAdd(&Ut[(size_t)t * 128 + pid], u);
  }
  // V partial: t = grp*96 + (m_l*3+c), each sums 32 n's
  {
    int grp = t / 96, mc = t % 96, m_l = mc / 3, c = mc % 3;
    const float* tp = &tile[m_l * LSTR + c];
    float vsp = 0.f;
#pragma unroll 8
    for (int j = 0; j < 32; ++j) vsp += tp[(grp * 32 + j) * 3];
    red[t] = vsp;
  }
  // cmean wave-reduce
  {
    float x = cm;
    for (int off = 32; off > 0; off >>= 1) x += __shfl_down(x, off);
    if ((t & 63) == 0) cred[t >> 6] = x;
  }
  __syncthreads();  // S2
  if (t < 96) {
    float vs = red[t] + red[96 + t] + red[192 + t] + red[288 + t];
    ycat[384 + t] = -vs;
  }
  if (t == 0) {
    float s = cred[0] + cred[1] + cred[2] + cred[3] + cred[4] + cred[5];
    atomicAdd(&cmean[pid], s);
  }
  __syncthreads();  // S3
  if (t < 3) {
    float sv = 0.f;
#pragma unroll 8
    for (int j = 0; j < 32; ++j) sv += ycat[384 + t + 3 * j];
    atomicAdd(&V2c[t * 128 + pid], -sv);
  }
  // gamma contribution: thread (b = t/6, j = t%6) dots 80 of the 480 elements
  {
    const int b = t / 6, j = t - (t / 6) * 6;
    const float* xb = X + (size_t)b * 2496;
    const int i0 = j * 80;
    float s = 0.f;
#pragma unroll 5
    for (int i = 0; i < 80; i += 4) {
      int e = i0 + i;
      // Xcat[e] = obj[b][e] for e<384, sa0[b][chunk*32*3 + (e-384)] for e>=384
      const float* xp = (e < 384) ? (xb + e) : (xb + chunk * 96 + e);
      float4 xv = *(const float4*)xp;
      float4 yv = *(const float4*)(&ycat[e]);
      s += xv.x * yv.x + xv.y * yv.y + xv.z * yv.z + xv.w * yv.w;
    }
    red[t] = s;
  }
  __syncthreads();  // S4
  if (t < 64) {
    const float* r6 = &red[t * 6];
    float g = r6[0] + r6[1] + r6[2] + r6[3] + r6[4] + r6[5];
    atomicAdd(&gWS[t * 128 + pid], g);
  }
}

// ---------------------------------------------------------------- 3x3 SVD -> rotation (Kabsch w/ reflection fix)
__device__ inline double det3(const double A[3][3]) {
  return A[0][0] * (A[1][1] * A[2][2] - A[1][2] * A[2][1])
       - A[0][1] * (A[1][0] * A[2][2] - A[1][2] * A[2][0])
       + A[0][2] * (A[1][0] * A[2][1] - A[1][1] * A[2][0]);
}

__device__ void svd3_rotation(const float* S, float* Rout) {
  double M[3][3], B[3][3], Vv[3][3];
  for (int i = 0; i < 3; ++i)
    for (int j = 0; j < 3; ++j) M[i][j] = (double)S[i * 3 + j];
  for (int i = 0; i < 3; ++i)
    for (int j = 0; j < 3; ++j) {
      double a = 0;
      for (int k = 0; k < 3; ++k) a += M[k][i] * M[k][j];
      B[i][j] = a;
    }
  for (int i = 0; i < 3; ++i)
    for (int j = 0; j < 3; ++j) Vv[i][j] = (i == j) ? 1.0 : 0.0;
  const int PP[3] = {0, 0, 1}, QQ[3] = {1, 2, 2};
  for (int sweep = 0; sweep < 25; ++sweep) {
    double off = B[0][1] * B[0][1] + B[0][2] * B[0][2] + B[1][2] * B[1][2];
    double dg = B[0][0] * B[0][0] + B[1][1] * B[1][1] + B[2][2] * B[2][2];
    if (off <= 1e-28 * (dg + 1e-300)) break;
    for (int pr = 0; pr < 3; ++pr) {
      int p = PP[pr], q = QQ[pr];
      double apq = B[p][q];
      if (apq == 0.0) continue;
      double dd = (B[p][p] - B[q][q]) / (2.0 * apq);
      double tt = 1.0 / (fabs(dd) + sqrt(dd * dd + 1.0));
      if (dd < 0.0) tt = -tt;
      double cc = 1.0 / sqrt(tt * tt + 1.0), ss = tt * cc;
      B[p][p] += tt * apq;
      B[q][q] -= tt * apq;
      B[p][q] = B[q][p] = 0.0;
      int k = 3 - p - q;
      double Bkp = cc * B[k][p] + ss * B[k][q];
      double Bkq = -ss * B[k][p] + cc * B[k][q];
      B[k][p] = B[p][k] = Bkp;
      B[k][q] = B[q][k] = Bkq;
      for (int i = 0; i < 3; ++i) {
        double vip = cc * Vv[i][p] + ss * Vv[i][q];
        double viq = -ss * Vv[i][p] + cc * Vv[i][q];
        Vv[i][p] = vip;
        Vv[i][q] = viq;
      }
    }
  }
  double lam[3] = {B[0][0], B[1][1], B[2][2]};
  int o0 = 0, o1 = 1, o2 = 2, tp;
  if (lam[o0] < lam[o1]) { tp = o0; o0 = o1; o1 = tp; }
  if (lam[o0] < lam[o2]) { tp = o0; o0 = o2; o2 = tp; }
  if (lam[o1] < lam[o2]) { tp = o1; o1 = o2; o2 = tp; }
  int ord[3] = {o0, o1, o2};
  double sv[3], U[3][3], Vs[3][3];
  for (int j = 0; j < 3; ++j) {
    double l = lam[ord[j]];
    sv[j] = l > 0.0 ? sqrt(l) : 0.0;
    for (int i = 0; i < 3; ++i) Vs[i][j] = Vv[i][ord[j]];
  }
  for (int j = 0; j < 3; ++j) {
    double vx = Vs[0][j], vy = Vs[1][j], vz = Vs[2][j];
    double ux = M[0][0] * vx + M[0][1] * vy + M[0][2] * vz;
    double uy = M[1][0] * vx + M[1][1] * vy + M[1][2] * vz;
    double uz = M[2][0] * vx + M[2][1] * vy + M[2][2] * vz;
    double sj = sv[j];
    if (sj > 1e-12 * (sv[0] + 1e-300)) {
      U[0][j] = ux / sj; U[1][j] = uy / sj; U[2][j] = uz / sj;
    } else if (j == 2) {
      double cx = U[1][0] * U[2][1] - U[2][0] * U[1][1];
      double cy = U[2][0] * U[0][1] - U[0][0] * U[2][1];
      double cz = U[0][0] * U[1][1] - U[1][0] * U[0][1];
      double nn = sqrt(cx * cx + cy * cy + cz * cz);
      if (nn < 1e-300) { cx = 0; cy = 0; cz = 1; nn = 1; }
      U[0][2] = cx / nn; U[1][2] = cy / nn; U[2][2] = cz / nn;
    } else {
      U[0][j] = (j == 0) ? 1.0 : 0.0;
      U[1][j] = (j == 1) ? 1.0 : 0.0;
      U[2][j] = 0.0;
    }
  }
  double dsgn = (det3(U) * det3(Vs)) < 0.0 ? -1.0 : 1.0;
  for (int i = 0; i < 3; ++i)
    for (int j = 0; j < 3; ++j)
      Rout[i * 3 + j] = (float)(U[i][0] * Vs[j][0] + U[i][1] * Vs[j][1] +
                                dsgn * U[i][2] * Vs[j][2]);
}

// ---------------------------------------------------------------- K3: finalize per batch
__global__ __launch_bounds__(384) void k_finish(
    const float* __restrict__ betas, const float* __restrict__ org,
    const float* __restrict__ JJ, const float* __restrict__ cmean,
    const float* __restrict__ Mc, const float* __restrict__ V2c,
    const float* __restrict__ saSum, const float* __restrict__ gWS,
    const float* __restrict__ Ut, float* __restrict__ out) {
  const int b = blockIdx.x, t = threadIdx.x;
  __shared__ float orgL[384], A[384], gammaL[128];
  __shared__ float betasL[10], J0L[3], cQ[3], smat[9], RL[9];

  if (t < 10) betasL[t] = betas[b * 10 + t];
  orgL[t] = org[(size_t)b * 384 + t];
  __syncthreads();
  if (t < 3) {
    float j0 = JJ[t];
#pragma unroll
    for (int k = 0; k < KB; ++k) j0 += betasL[k] * JJ[3 + t * KB + k];
    J0L[t] = j0;
    float s = 0.f;
    for (int n = 0; n < N_A; ++n) s += orgL[n * 3 + t];
    cQ[t] = s * (1.f / 128.f);
  }
  __syncthreads();

  if (t < 128) {
    float g = gWS[b * 128 + t] + J0L[0] * V2c[t] + J0L[1] * V2c[128 + t] +
              J0L[2] * V2c[256 + t] - cmean[t];
    gammaL[t] = g;
    out[b * 128 + t] = g;  // output 0
  }
  __syncthreads();

  // A[n,c] = Mc + sum_p gamma[p]*Ut[nc][p]
  {
    const float4* up4 = (const float4*)(Ut + (size_t)t * 128);
    float gs = 0.f;
#pragma unroll 8
    for (int i = 0; i < 32; ++i) {
      float4 u4 = up4[i];
      gs += gammaL[4 * i] * u4.x + gammaL[4 * i + 1] * u4.y +
            gammaL[4 * i + 2] * u4.z + gammaL[4 * i + 3] * u4.w;
    }
    A[t] = Mc[t] + gs;
  }
  __syncthreads();

  if (t < 9) {
    int c = t / 3, d = t % 3;
    float s = 0.f, cq = cQ[d];
    for (int n = 0; n < N_A; ++n) s += A[n * 3 + c] * (orgL[n * 3 + d] - cq);
    smat[t] = s;
  }
  __syncthreads();
  if (t == 0) svd3_rotation(smat, RL);
  __syncthreads();
  if (t < 9) out[8192 + b * 9 + t] = RL[t];  // output 1
  if (t < 3) {
    float s2 = 0.f;
    for (int n = 0; n < N_A; ++n) s2 += A[n * 3 + t];
    float meanP = saSum[b * 3 + t] * (1.f / 704.f) - J0L[t] + s2 * (1.f / 90112.f);
    float rq = RL[t * 3 + 0] * cQ[0] + RL[t * 3 + 1] * cQ[1] + RL[t * 3 + 2] * cQ[2];
    out[8768 + b * 3 + t] = meanP - rq;  // output 2
  }
}

// ----------------------------------------------------------------
extern "C" void kernel_launch(void* const* d_in, const int* in_sizes, int n_in,
                              void* d_out, int out_size, void* d_ws, size_t ws_size,
                              hipStream_t stream) {
  const float* betas = (const float*)d_in[0];
  const float* rot   = (const float*)d_in[1];
  const float* trans = (const float*)d_in[2];
  const float* org   = (const float*)d_in[3];
  const float* vt    = (const float*)d_in[4];
  const float* sd    = (const float*)d_in[5];
  const float* Jr    = (const float*)d_in[6];
  const float* mean  = (const float*)d_in[7];
  const float* pc    = (const float*)d_in[8];
  const int*   anch  = (const int*)d_in[9];
  float* out = (float*)d_out;
  float* ws  = (float*)d_ws;
  if (ws_size < (size_t)WS_TOTAL * sizeof(float)) return;  // need ~0.9 MB scratch

  float* JJ    = ws + WS_JJ;
  float* cmean = ws + WS_CMEAN;
  float* Mc    = ws + WS_MC;
  float* V2c   = ws + WS_V2C;
  float* saSum = ws + WS_SASUM;
  float* gWS   = ws + WS_GWS;
  float* Ut    = ws + WS_UT;
  float* X     = ws + WS_X;

  hipMemsetAsync(ws, 0, (size_t)WS_ZEROF * sizeof(float), stream);
  k_pre<<<NJ_BLK + NM_BLK + NP_BLK, 384, 0, stream>>>(
      Jr, vt, sd, mean, betas, rot, trans, org, anch, JJ, Mc, X, saSum);
  k_main<<<NCHUNK * 128, 384, 0, stream>>>(pc, mean, X, Ut, V2c, cmean, gWS);
  k_finish<<<64, 384, 0, stream>>>(betas, org, JJ, cmean, Mc, V2c, saSum, gWS,
                                   Ut, out);
}